// Round 1
// baseline (74.888 us; speedup 1.0000x reference)
//
#include <hip/hip_runtime.h>
#include <hip/hip_bf16.h>

#define M_DIM 500000
#define NPER  21
#define NELEM (M_DIM * NPER)     // 10,500,000 floats per (tensor, group)
#define NF4   (NELEM / 4)        // 2,625,000 float4s
#define NBLK  256
#define TPB   252                // 12 m-rows * 21; block reads 1008 contiguous floats/iter

__device__ __forceinline__ float sigmoidf(float x) {
    return 1.0f / (1.0f + __expf(-x));
}

// One block-column per (tensor, group). Each thread owns 4 fixed p-residues.
__global__ __launch_bounds__(TPB) void probs_reduce_kernel(
    const float* __restrict__ ST0, const float* __restrict__ W0,
    const float* __restrict__ ST1, const float* __restrict__ W1,
    const float* __restrict__ BEV, const float* __restrict__ BEVp,
    const float* __restrict__ Bp, float* __restrict__ tmp)
{
    const int t   = threadIdx.x;
    const int tau = blockIdx.y >> 2;   // 0: (ST0,W0)  1: (ST1,W1)
    const int grp = blockIdx.y & 3;

    const float* ST = (tau == 0 ? ST0 : ST1) + grp * M_DIM;
    const float4* W = (const float4*)((tau == 0 ? W0 : W1) + (size_t)grp * NELEM);

    const float B    = Bp[0];
    const float base = fmaxf(BEVp[0], 0.0f) * BEV[0];

    const int g0 = blockIdx.x * TPB + t;
    const int S  = NBLK * TPB;         // 64512 float4s; 4*S % 21 == 0 -> r constant/thread

    float acc0 = 0.f, acc1 = 0.f, acc2 = 0.f, acc3 = 0.f;

    for (int f = g0; f < NF4; f += S) {
        float4 w = W[f];
        int e0 = f * 4;
        int m0 = (int)((unsigned)e0 / 21u);
        int r  = e0 - m0 * 21;                 // 0..20, invariant across iters
        int m1 = m0 + 1; if (m1 >= M_DIM) m1 = M_DIM - 1;  // guard OOB (value unused then)
        float s0 = sigmoidf(B * (base + ST[m0]));
        float s1 = sigmoidf(B * (base + ST[m1]));
        acc0 += w.x * ((r + 0 < 21) ? s0 : s1);
        acc1 += w.y * ((r + 1 < 21) ? s0 : s1);
        acc2 += w.z * ((r + 2 < 21) ? s0 : s1);
        acc3 += w.w * ((r + 3 < 21) ? s0 : s1);
    }

    // element (t, j) has p = (4t + j) % 21 == (LDS index) % 21 since 1008 % 21 == 0
    __shared__ float sm[TPB * 4];
    sm[t * 4 + 0] = acc0;
    sm[t * 4 + 1] = acc1;
    sm[t * 4 + 2] = acc2;
    sm[t * 4 + 3] = acc3;
    __syncthreads();

    if (t < NPER) {
        float s = 0.f;
        #pragma unroll
        for (int q = 0; q < (TPB * 4) / NPER; ++q)   // 48 entries per residue
            s += sm[t + NPER * q];
        atomicAdd(&tmp[blockIdx.y * NPER + t], s);
    }
}

__global__ void probs_final_kernel(const float* __restrict__ tmp,
                                   const float* __restrict__ pp,   // (5,4)
                                   float* __restrict__ out)
{
    __shared__ float red[128];
    const int t = threadIdx.x;
    float val = 0.f;
    if (t < 84) {
        const int i = t / 21, inner = t % 21;
        float Pk[5];
        #pragma unroll
        for (int k = 0; k < 5; ++k) {
            float a0 = pp[k*4+0], a1 = pp[k*4+1], a2 = pp[k*4+2], a3 = pp[k*4+3];
            float mx = fmaxf(fmaxf(a0, a1), fmaxf(a2, a3));
            float e0 = __expf(a0-mx), e1 = __expf(a1-mx), e2 = __expf(a2-mx), e3 = __expf(a3-mx);
            float inv = 1.0f / (e0 + e1 + e2 + e3);
            float q0 = e0*inv, q1 = e1*inv, q2 = e2*inv, q3 = e3*inv;
            float q[4] = {q0, q1, q2, q3};
            float v = q[i];
            if (inner > 0) {
                int jj = (inner - 1) / 5, kk = (inner - 1) % 5;
                v *= q[jj];
                if (kk > 0) v *= q[kk - 1];
            }
            Pk[k] = v;
        }
        float t0 = tmp[t], t1 = tmp[84 + t];
        val = Pk[0] * t0 + (Pk[1] + Pk[2] + Pk[3] + Pk[4]) * t1;
    }
    red[t] = val;
    __syncthreads();
    #pragma unroll
    for (int s = 64; s > 0; s >>= 1) {
        if (t < s) red[t] += red[t + s];
        __syncthreads();
    }
    if (t == 0) out[0] = red[0] * 0.2f;   // mean over 5 outs
}

extern "C" void kernel_launch(void* const* d_in, const int* in_sizes, int n_in,
                              void* d_out, int out_size, void* d_ws, size_t ws_size,
                              hipStream_t stream) {
    const float* BEV  = (const float*)d_in[0];
    const float* ST0  = (const float*)d_in[1];
    const float* W0   = (const float*)d_in[2];
    const float* ST1  = (const float*)d_in[3];
    const float* W1   = (const float*)d_in[4];
    const float* pp   = (const float*)d_in[5];
    const float* BEVp = (const float*)d_in[6];
    const float* B    = (const float*)d_in[7];
    float* out = (float*)d_out;
    float* tmp = (float*)d_ws;   // 168 floats: tmp0[84] then tmp1[84]

    hipMemsetAsync(tmp, 0, 168 * sizeof(float), stream);
    probs_reduce_kernel<<<dim3(NBLK, 8), TPB, 0, stream>>>(ST0, W0, ST1, W1,
                                                           BEV, BEVp, B, tmp);
    probs_final_kernel<<<1, 128, 0, stream>>>(tmp, pp, out);
}